// Round 14
// baseline (20.765 us; speedup 1.0000x reference)
//
#include <hip/hip_runtime.h>

#define NN 1024
#define DD 64
#define NF 11
#define TI 4
#define BT 1024

// Softmax-without-max is exact here: valid scores are in (-1, 0], masked keys
// contribute exactly +0.0, len >= 1 so every row-sum > 0.
//
// R14 = R13 (cross-gen drain overlap + wave-dead skip) with FOUR dispatch
// generations (TI=4, grid=2048): per-gen store drain ~1.3us, only the final
// one exposed; gen g's drain hides under gen g+1's fj-load/compute. Dead
// blocks retire early -> scheduler backfills from next gen.
__global__ __launch_bounds__(BT, 8) void featuresim_kernel(
    const float* __restrict__ x,
    const int* __restrict__ x_lengths,
    const float* __restrict__ fimp,
    float* __restrict__ out)
{
    const int tid = threadIdx.x;
    const int b   = blockIdx.x >> 8;            // 256 row-groups per batch
    const int i0  = (blockIdx.x & 255) * TI;
    const int len = x_lengths[b];

    // wave-uniform: this wave's 64 keys are all masked -> all outputs 0
    const bool wave_dead = (tid & ~63) >= len;

    __shared__ float partials[TI][BT];    // 16 KiB
    __shared__ float totals[TI];

    float e[TI];

    if (wave_dead) {
        #pragma unroll
        for (int r = 0; r < TI; ++r) {
            e[r] = 0.0f;
            partials[r][tid] = 0.0f;
        }
    } else {
        // feature_importance: uniform -> SGPRs
        float fi[NF];
        #pragma unroll
        for (int k = 0; k < NF; ++k) fi[k] = fimp[k];

        // this thread's key row j = tid
        float fj[NF];
        {
            const float4* p = reinterpret_cast<const float4*>(
                x + (size_t)(b * NN + tid) * DD);
            float4 a = p[0], c = p[1], d = p[2];
            fj[0] = a.x; fj[1] = a.y; fj[2]  = a.z; fj[3] = a.w;
            fj[4] = c.x; fj[5] = c.y; fj[6]  = c.z; fj[7] = c.w;
            fj[8] = d.x; fj[9] = d.y; fj[10] = d.z;
        }
        const bool valid = tid < len;   // partial wave masks per-lane

        #pragma unroll
        for (int r = 0; r < TI; ++r) {
            const float* qp = x + (size_t)(b * NN + i0 + r) * DD;  // uniform -> s_load
            float s = 0.0f;
            #pragma unroll
            for (int k = 0; k < NF; ++k) {
                float d = qp[k] - fj[k];
                s = fmaf(-fabsf(d), fi[k], s);     // -abs() via VOP3 input mod
            }
            float val = (s > -1.0f) ? s : 0.0f;
            float ev  = valid ? __expf(val) : 0.0f;
            e[r] = ev;
            partials[r][tid] = ev;
        }
    }
    __syncthreads();                      // (1) partials ready (no stores yet)

    // ---- phase 2: waves 0-3 reduce one row each via 4x ds_read_b128
    const int lane = tid & 63;
    const int wid  = tid >> 6;
    if (wid < TI) {
        float s = 0.0f;
        #pragma unroll
        for (int m = 0; m < 4; ++m) {
            float4 v4 = *reinterpret_cast<const float4*>(
                &partials[wid][lane * 4 + 256 * m]);
            s += (v4.x + v4.y) + (v4.z + v4.w);
        }
        #pragma unroll
        for (int off = 32; off >= 1; off >>= 1)
            s += __shfl_xor(s, off, 64);
        if (lane == 0) totals[wid] = s;
    }
    __syncthreads();                      // (2) totals ready (still no stores issued)

    // ---- phase 3: normalize + coalesced dword stores; kernel ends with
    // stores in flight -> drain overlaps the next generation.
    if (wave_dead) {
        #pragma unroll
        for (int r = 0; r < TI; ++r)
            out[(size_t)(b * NN + i0 + r) * NN + tid] = 0.0f;
    } else {
        #pragma unroll
        for (int r = 0; r < TI; ++r) {
            const float inv = __builtin_amdgcn_rcpf(totals[r]);
            out[(size_t)(b * NN + i0 + r) * NN + tid] = e[r] * inv;
        }
    }
}

extern "C" void kernel_launch(void* const* d_in, const int* in_sizes, int n_in,
                              void* d_out, int out_size, void* d_ws, size_t ws_size,
                              hipStream_t stream) {
    const float* x    = (const float*)d_in[0];
    const int*   xlen = (const int*)d_in[1];
    const float* fimp = (const float*)d_in[2];
    float*       out  = (float*)d_out;

    const int B = in_sizes[1];                  // 8
    dim3 grid(B * (NN / TI));                   // 2048 blocks = 4 generations
    dim3 block(BT);
    featuresim_kernel<<<grid, block, 0, stream>>>(x, xlen, fimp, out);
}

// Round 15
// 17.308 us; speedup vs baseline: 1.1998x; 1.1998x over previous
//
#include <hip/hip_runtime.h>

#define NN 1024
#define DD 64
#define NF 11
#define R1 10         // rows per gen-1 block
#define R2 6          // rows per gen-2 block
#define MAXR 10
#define BT 1024

// Softmax-without-max is exact here: valid scores are in (-1, 0], masked keys
// contribute exactly +0.0, len >= 1 so every row-sum > 0.
//
// R15 = R13 (2 generations + wave-dead skip) with an ASYMMETRIC row split:
// gen-1 blocks (0..511, launched first -> first resident generation) take 10
// rows; gen-2 blocks take 6. Total slab traffic unchanged vs R13; gen-2's
// exposed final store drain shrinks 16.8->12.6MB while gen-1's larger drain
// still hides under gen-2's startup+compute. Per batch: 64x10 + 64x6 = 1024,
// no block crosses a batch boundary (fj stays single-batch per block).
// Row loops are compile-time unrolled over MAXR with wave-uniform r<nrows
// guards so e[] stays statically indexed (no scratch).
__global__ __launch_bounds__(BT, 8) void featuresim_kernel(
    const float* __restrict__ x,
    const int* __restrict__ x_lengths,
    const float* __restrict__ fimp,
    float* __restrict__ out)
{
    const int tid = threadIdx.x;

    int b, i0, nrows;
    if (blockIdx.x < 512) {                     // generation 1: heavy blocks
        b     = blockIdx.x >> 6;
        i0    = (blockIdx.x & 63) * R1;         // rows [0, 640)
        nrows = R1;
    } else {                                    // generation 2: light blocks
        const int bb = blockIdx.x - 512;
        b     = bb >> 6;
        i0    = 640 + (bb & 63) * R2;           // rows [640, 1024)
        nrows = R2;
    }
    const int len = x_lengths[b];

    // wave-uniform: this wave's 64 keys are all masked -> all outputs 0
    const bool wave_dead = (tid & ~63) >= len;

    __shared__ float partials[MAXR][BT];  // 40 KiB -> 2 blocks/CU co-resident
    __shared__ float totals[MAXR];

    float e[MAXR];

    if (wave_dead) {
        #pragma unroll
        for (int r = 0; r < MAXR; ++r) {
            if (r < nrows) {
                e[r] = 0.0f;
                partials[r][tid] = 0.0f;
            }
        }
    } else {
        // feature_importance: uniform -> SGPRs
        float fi[NF];
        #pragma unroll
        for (int k = 0; k < NF; ++k) fi[k] = fimp[k];

        // this thread's key row j = tid
        float fj[NF];
        {
            const float4* p = reinterpret_cast<const float4*>(
                x + (size_t)(b * NN + tid) * DD);
            float4 a = p[0], c = p[1], d = p[2];
            fj[0] = a.x; fj[1] = a.y; fj[2]  = a.z; fj[3] = a.w;
            fj[4] = c.x; fj[5] = c.y; fj[6]  = c.z; fj[7] = c.w;
            fj[8] = d.x; fj[9] = d.y; fj[10] = d.z;
        }
        const bool valid = tid < len;   // partial wave masks per-lane

        #pragma unroll
        for (int r = 0; r < MAXR; ++r) {
            if (r < nrows) {            // wave-uniform guard (s_cbranch)
                const float* qp = x + (size_t)(b * NN + i0 + r) * DD;  // s_load
                float s = 0.0f;
                #pragma unroll
                for (int k = 0; k < NF; ++k) {
                    float d = qp[k] - fj[k];
                    s = fmaf(-fabsf(d), fi[k], s);   // -abs() via VOP3 input mod
                }
                float val = (s > -1.0f) ? s : 0.0f;
                float ev  = valid ? __expf(val) : 0.0f;
                e[r] = ev;
                partials[r][tid] = ev;
            }
        }
    }
    __syncthreads();                      // (1) partials ready (no stores yet)

    // ---- phase 2: waves 0..nrows-1 reduce one row each via 4x ds_read_b128
    const int lane = tid & 63;
    const int wid  = tid >> 6;
    if (wid < nrows) {
        float s = 0.0f;
        #pragma unroll
        for (int m = 0; m < 4; ++m) {
            float4 v4 = *reinterpret_cast<const float4*>(
                &partials[wid][lane * 4 + 256 * m]);
            s += (v4.x + v4.y) + (v4.z + v4.w);
        }
        #pragma unroll
        for (int off = 32; off >= 1; off >>= 1)
            s += __shfl_xor(s, off, 64);
        if (lane == 0) totals[wid] = s;
    }
    __syncthreads();                      // (2) totals ready (still no stores)

    // ---- phase 3: normalize + coalesced dword stores; kernel ends with
    // stores in flight -> gen-1 drain overlaps gen-2 startup/compute.
    if (wave_dead) {
        #pragma unroll
        for (int r = 0; r < MAXR; ++r)
            if (r < nrows)
                out[(size_t)(b * NN + i0 + r) * NN + tid] = 0.0f;
    } else {
        #pragma unroll
        for (int r = 0; r < MAXR; ++r) {
            if (r < nrows) {
                const float inv = __builtin_amdgcn_rcpf(totals[r]);
                out[(size_t)(b * NN + i0 + r) * NN + tid] = e[r] * inv;
            }
        }
    }
}

extern "C" void kernel_launch(void* const* d_in, const int* in_sizes, int n_in,
                              void* d_out, int out_size, void* d_ws, size_t ws_size,
                              hipStream_t stream) {
    const float* x    = (const float*)d_in[0];
    const int*   xlen = (const int*)d_in[1];
    const float* fimp = (const float*)d_in[2];
    float*       out  = (float*)d_out;

    dim3 grid(1024);                      // 512 gen-1 + 512 gen-2 blocks
    dim3 block(BT);
    featuresim_kernel<<<grid, block, 0, stream>>>(x, xlen, fimp, out);
}

// Round 16
// 16.891 us; speedup vs baseline: 1.2293x; 1.0247x over previous
//
#include <hip/hip_runtime.h>

#define NN 1024
#define DD 64
#define NF 11
#define TI 8
#define BT 1024

// Softmax-without-max is exact here: valid scores are in (-1, 0], masked keys
// contribute exactly +0.0, len >= 1 so every row-sum > 0.
//
// R16 = R13 (2 generations + wave-dead skip) with a ROW-OWNING EPILOGUE:
// after the single barrier, wave w reduces row w AND stores the whole row
// (it already holds the row's 16 float4 chunks in the registers it reduced).
// Barrier (2) + the all-wave phase-3 are gone; reducer waves desync; waves
// 8-15 retire at the barrier, freeing slots for the next generation early.
// Output is bit-identical to R13 (same sum order, same products).
__global__ __launch_bounds__(BT, 8) void featuresim_kernel(
    const float* __restrict__ x,
    const int* __restrict__ x_lengths,
    const float* __restrict__ fimp,
    float* __restrict__ out)
{
    const int tid = threadIdx.x;
    const int b   = blockIdx.x >> 7;            // 128 row-groups per batch
    const int i0  = (blockIdx.x & 127) * TI;
    const int len = x_lengths[b];

    // wave-uniform: this wave's 64 keys are all masked -> all outputs 0
    const bool wave_dead = (tid & ~63) >= len;

    __shared__ float partials[TI][BT];    // 32 KiB -> 2 blocks/CU co-resident

    if (wave_dead) {
        #pragma unroll
        for (int r = 0; r < TI; ++r)
            partials[r][tid] = 0.0f;
    } else {
        // feature_importance: uniform -> SGPRs
        float fi[NF];
        #pragma unroll
        for (int k = 0; k < NF; ++k) fi[k] = fimp[k];

        // this thread's key row j = tid
        float fj[NF];
        {
            const float4* p = reinterpret_cast<const float4*>(
                x + (size_t)(b * NN + tid) * DD);
            float4 a = p[0], c = p[1], d = p[2];
            fj[0] = a.x; fj[1] = a.y; fj[2]  = a.z; fj[3] = a.w;
            fj[4] = c.x; fj[5] = c.y; fj[6]  = c.z; fj[7] = c.w;
            fj[8] = d.x; fj[9] = d.y; fj[10] = d.z;
        }
        const bool valid = tid < len;   // partial wave masks per-lane

        #pragma unroll
        for (int r = 0; r < TI; ++r) {
            const float* qp = x + (size_t)(b * NN + i0 + r) * DD;  // uniform -> s_load
            float s = 0.0f;
            #pragma unroll
            for (int k = 0; k < NF; ++k) {
                float d = qp[k] - fj[k];
                s = fmaf(-fabsf(d), fi[k], s);     // -abs() via VOP3 input mod
            }
            float val = (s > -1.0f) ? s : 0.0f;
            partials[r][tid] = valid ? __expf(val) : 0.0f;
        }
    }
    __syncthreads();                      // the ONLY barrier (no stores before it)

    // ---- epilogue: wave w owns row w end-to-end; waves 8-15 retire now
    const int lane = tid & 63;
    const int wid  = tid >> 6;
    if (wid < TI) {
        // read row w's 4KB as 4 float4 chunks (kept for the store)
        float4 v[4];
        float s = 0.0f;
        #pragma unroll
        for (int m = 0; m < 4; ++m) {
            if (256 * m < len) {          // wave-uniform; skipped chunks are all 0
                v[m] = *reinterpret_cast<const float4*>(
                    &partials[wid][lane * 4 + 256 * m]);
            } else {
                v[m] = make_float4(0.0f, 0.0f, 0.0f, 0.0f);
            }
            s += (v[m].x + v[m].y) + (v[m].z + v[m].w);
        }
        #pragma unroll
        for (int off = 32; off >= 1; off >>= 1)
            s += __shfl_xor(s, off, 64);

        const float inv = __builtin_amdgcn_rcpf(s);
        float4* rowp = reinterpret_cast<float4*>(
            out + (size_t)(b * NN + i0 + wid) * NN);
        #pragma unroll
        for (int m = 0; m < 4; ++m) {
            float4 o = make_float4(v[m].x * inv, v[m].y * inv,
                                   v[m].z * inv, v[m].w * inv);
            rowp[lane + 64 * m] = o;      // 1KB per wave-instr, coalesced
        }
    }
    // kernel ends with stores in flight -> drain overlaps the next generation
}

extern "C" void kernel_launch(void* const* d_in, const int* in_sizes, int n_in,
                              void* d_out, int out_size, void* d_ws, size_t ws_size,
                              hipStream_t stream) {
    const float* x    = (const float*)d_in[0];
    const int*   xlen = (const int*)d_in[1];
    const float* fimp = (const float*)d_in[2];
    float*       out  = (float*)d_out;

    const int B = in_sizes[1];                  // 8
    dim3 grid(B * (NN / TI));                   // 1024 blocks = 2 generations
    dim3 block(BT);
    featuresim_kernel<<<grid, block, 0, stream>>>(x, xlen, fimp, out);
}